// Round 10
// baseline (507.791 us; speedup 1.0000x reference)
//
#include <hip/hip_runtime.h>
#include <hip/hip_bf16.h>

#define I_SZ 834
#define H_SZ 190
#define F_SZ 250
#define O_SZ 512
#define T_SZ 256
#define K_SZ 1024   // I+H
#define NW   47500  // F*H: Wupd flat IS W3[1024][47500] row-major

// Abf2 layout: value A[t][k] (bf16 of concat(x_t,h_t)) lives at
//   (k>>3)*2048 + t*8 + (k&7)   -> b128 fragment loads are 256-B coalesced,
//   and 4 consecutive k-slabs = 16 KB contiguous (one K-stage of staging).

typedef __attribute__((ext_vector_type(8))) short short8;
typedef __attribute__((ext_vector_type(4))) float f32x4;

__device__ __forceinline__ short f2bf(float f) {
    union { __hip_bfloat16 h; short s; } u;
    u.h = __float2bfloat16(f);
    return u.s;
}
__device__ __forceinline__ float bf2f(short s) {
    union { short s; __hip_bfloat16 h; } u;
    u.s = s;
    return __bfloat162float(u.h);
}

// async global->LDS, 16B per lane; LDS dest = wave-uniform base + lane*16
__device__ __forceinline__ void gll16(const void* g, void* l) {
    __builtin_amdgcn_global_load_lds(
        (const __attribute__((address_space(1))) void*)g,
        (__attribute__((address_space(3))) void*)l, 16, 0, 0);
}

// LDS-only barrier: drain lgkm (ds ops) but NOT vmcnt (global stores keep
// flying). __syncthreads would emit s_waitcnt vmcnt(0) -> ~300cy store drain
// on the scan's serial critical path.
__device__ __forceinline__ void lds_barrier() {
    asm volatile("s_waitcnt lgkmcnt(0)" ::: "memory");
    __builtin_amdgcn_s_barrier();
}

// -------- K2b: x-part of Abf2 + zero pad k in [834,864) ---------------------
__global__ void __launch_bounds__(256) k2b_buildAx(const float* __restrict__ x,
                                                   short* __restrict__ Abf2) {
    int t = blockIdx.x;
    for (int i = threadIdx.x; i < I_SZ; i += 256)
        Abf2[(i >> 3) * (T_SZ * 8) + t * 8 + (i & 7)] = f2bf(x[t * I_SZ + i]);
    for (int i = I_SZ + threadIdx.x; i < 864; i += 256)
        Abf2[(i >> 3) * (T_SZ * 8) + t * 8 + (i & 7)] = 0;
}

// -------- K1: P^T[h][t] = Wx^T @ x^T via MFMA (12 blocks x 4 waves) ---------
__global__ void __launch_bounds__(256) k1_mfma(const short* __restrict__ Abf2,
                                               const float* __restrict__ Wrnn,
                                               const float* __restrict__ brnn,
                                               float* __restrict__ P) {
    const int tid = threadIdx.x;
    const int bh = blockIdx.x;
    const int w = tid >> 6, l = tid & 63;
    const int l15 = l & 15, lg = l >> 4;
    const int h = bh * 16 + l15;
    const int hc = (h < H_SZ) ? h : H_SZ - 1;

    f32x4 acc[4];
    #pragma unroll
    for (int tt = 0; tt < 4; ++tt) acc[tt] = (f32x4){0.f, 0.f, 0.f, 0.f};

    for (int ks = 0; ks < 27; ++ks) {       // K = 864 (zero-padded past 834)
        short8 afr;
        #pragma unroll
        for (int e = 0; e < 8; ++e) {
            const int kk = ks * 32 + lg * 8 + e;
            float v = (kk < I_SZ && h < H_SZ) ? Wrnn[hc * K_SZ + H_SZ + kk] : 0.f;
            afr[e] = f2bf(v);
        }
        #pragma unroll
        for (int tt = 0; tt < 4; ++tt) {
            const short* ap = Abf2 + (size_t)(ks * 4 + lg) * (T_SZ * 8)
                                   + (size_t)(w * 64 + tt * 16 + l15) * 8;
            short8 bfr = *reinterpret_cast<const short8*>(ap);
            acc[tt] = __builtin_amdgcn_mfma_f32_16x16x32_bf16(afr, bfr, acc[tt], 0, 0, 0);
        }
    }
    #pragma unroll
    for (int tt = 0; tt < 4; ++tt) {
        const int t = w * 64 + tt * 16 + l15;
        #pragma unroll
        for (int r = 0; r < 4; ++r) {
            const int hrow = bh * 16 + lg * 4 + r;
            if (hrow < H_SZ) P[t * H_SZ + hrow] = acc[tt][r] + brnn[hrow];
        }
    }
}

// -------- K2 v4: MFMA scan, 4 waves split by n ONLY (48 n-cols, full k) -----
// Wave w: n in [w*48, w*48+48) = 3 n-tiles; B[6][3] = 72 VGPR; 6-deep MFMA
// chain does the whole k=192 reduction in-register (no cross-wave part[]).
// hlds ping-pong => ONE lgkm-only barrier per step; global stores (S, h_all,
// Abf2) never drained on the critical path.
__global__ void __launch_bounds__(256, 1) k2_scan(const float* __restrict__ Wrnn,
                                                  const float* __restrict__ h0,
                                                  const float* __restrict__ P,
                                                  float* __restrict__ h_all,
                                                  float* __restrict__ S,
                                                  short* __restrict__ Abf2) {
    __shared__ __align__(16) short hlds[2][192];
    const int tid = threadIdx.x;
    const int w = tid >> 6, l = tid & 63;
    const int l15 = l & 15, lg = l >> 4;
    const short8 zs = {0, 0, 0, 0, 0, 0, 0, 0};

    // one-time: this wave's Whh^T fragments (full k, quarter n)
    short8 B[6][3];
    #pragma unroll
    for (int kt = 0; kt < 6; ++kt) {
        #pragma unroll
        for (int nt = 0; nt < 3; ++nt) {
            const int n = w * 48 + nt * 16 + l15;
            short8 bf = zs;
            #pragma unroll
            for (int e = 0; e < 8; ++e) {
                const int kk = kt * 32 + lg * 8 + e;
                float v = (n < H_SZ && kk < H_SZ) ? Wrnn[n * K_SZ + kk] : 0.f;
                bf[e] = f2bf(v);
            }
            B[kt][nt] = bf;
        }
    }
    if (tid < 192) {
        hlds[0][tid] = f2bf((tid < H_SZ) ? h0[tid] : 0.f);
        hlds[1][tid] = 0;               // pad slots 190,191 stay 0 forever
    }
    float Srun[3] = {0.f, 0.f, 0.f};
    float pc[3];
    #pragma unroll
    for (int nt = 0; nt < 3; ++nt) {
        const int n = w * 48 + nt * 16 + l15;
        pc[nt] = (l < 16 && n < H_SZ) ? P[n] : 0.f;
    }
    lds_barrier();

    int rb = 0;
    for (int t = 0; t < T_SZ; ++t) {
        short8 a[6];
        #pragma unroll
        for (int kt = 0; kt < 6; ++kt) {
            short8 ar = *reinterpret_cast<const short8*>(&hlds[rb][kt * 32 + lg * 8]);
            a[kt] = (l15 == 0) ? ar : zs;
        }
        float pn[3];
        #pragma unroll
        for (int nt = 0; nt < 3; ++nt) {
            const int n = w * 48 + nt * 16 + l15;
            pn[nt] = (t + 1 < T_SZ && l < 16 && n < H_SZ) ? P[(t + 1) * H_SZ + n] : 0.f;
        }
        f32x4 acc[3];
        #pragma unroll
        for (int nt = 0; nt < 3; ++nt) {
            f32x4 c = {0.f, 0.f, 0.f, 0.f};
            #pragma unroll
            for (int kt = 0; kt < 6; ++kt)
                c = __builtin_amdgcn_mfma_f32_16x16x32_bf16(a[kt], B[kt][nt], c, 0, 0, 0);
            acc[nt] = c;
        }
        if (l < 16) {
            #pragma unroll
            for (int nt = 0; nt < 3; ++nt) {
                const int n = w * 48 + nt * 16 + l15;
                if (n < H_SZ) {
                    float v = tanhf(acc[nt][0] + pc[nt]);
                    S[t * H_SZ + n] = Srun[nt];      // prefix EXCLUDING current
                    h_all[t * H_SZ + n] = v;
                    const int k = I_SZ + n;
                    Abf2[(k >> 3) * (T_SZ * 8) + t * 8 + (k & 7)] = f2bf(v);
                    hlds[rb ^ 1][n] = f2bf(v);       // write buffer != read buffer
                    Srun[nt] += v;
                }
            }
        }
        lds_barrier();                               // one LDS-only barrier/step
        rb ^= 1;
        #pragma unroll
        for (int nt = 0; nt < 3; ++nt) pc[nt] = pn[nt];
    }
}

// -------- K3 v5: 2-phase gll-staged MFMA GEMM (zero global loads in K-loop) -
__global__ void __launch_bounds__(512) k3_mfma(const float* __restrict__ Wupd,
                                               const short* __restrict__ Abf2,
                                               const float* __restrict__ S,
                                               float* __restrict__ zprime) {
    __shared__ __align__(16) float Wlds[2][4096];    // [32 k][128 n] fp32
    __shared__ __align__(16) short Alds[2][8192];    // [4 g][256 t][8 k] bf16
    __shared__ float part[2][256];
    const int tid = threadIdx.x;
    const int bn0 = blockIdx.x * 128;
    const int l = tid & 63, wv = tid >> 6;
    const int l15 = l & 15, lg = l >> 4;

    part[tid >> 8][tid & 255] = 0.f;

    const char* src[4];
    long long stp[4];
    int cloc[4];
    #pragma unroll
    for (int i = 0; i < 4; ++i) {
        const int c = wv * 4 + i;
        cloc[i] = c;
        if (c < 16) {
            const int k = c * 2 + (l >> 5);          // 0..31
            const int n = (l & 31) * 4;              // 0..124
            const bool ok = (bn0 + n + 4) <= NW;     // NW % 4 == 0
            src[i] = (const char*)(Wupd + (size_t)k * NW + (ok ? (size_t)(bn0 + n) : 0));
            stp[i] = (long long)32 * NW * 4;
        } else {
            src[i] = (const char*)(Abf2 + (size_t)(c - 16) * 512 + (size_t)l * 8);
            stp[i] = 16384;
        }
    }

    f32x4 acc[16];
    #pragma unroll
    for (int tt = 0; tt < 16; ++tt) acc[tt] = (f32x4){0.f, 0.f, 0.f, 0.f};

    #pragma unroll
    for (int i = 0; i < 4; ++i) {
        void* dst = (cloc[i] < 16) ? (void*)&Wlds[0][cloc[i] * 256]
                                   : (void*)&Alds[0][(cloc[i] - 16) * 512];
        gll16(src[i], dst);
        src[i] += stp[i];
    }
    __syncthreads();

    int cur = 0;
    #pragma unroll 1
    for (int s = 0; s < 32; ++s) {
        if (s + 1 < 32) {                            // issue next stage FIRST
            #pragma unroll
            for (int i = 0; i < 4; ++i) {
                void* dst = (cloc[i] < 16) ? (void*)&Wlds[cur ^ 1][cloc[i] * 256]
                                           : (void*)&Alds[cur ^ 1][(cloc[i] - 16) * 512];
                gll16(src[i], dst);
                src[i] += stp[i];
            }
        }
        short8 afr;
        #pragma unroll
        for (int e = 0; e < 8; ++e)
            afr[e] = f2bf(Wlds[cur][(lg * 8 + e) * 128 + wv * 16 + l15]);
        #pragma unroll
        for (int tt = 0; tt < 16; ++tt) {
            short8 bfr = *reinterpret_cast<const short8*>(
                &Alds[cur][((size_t)lg * 256 + tt * 16 + l15) * 8]);
            acc[tt] = __builtin_amdgcn_mfma_f32_16x16x32_bf16(afr, bfr, acc[tt], 0, 0, 0);
        }
        __syncthreads();
        cur ^= 1;
    }

    const int jlo = bn0 / H_SZ;
    #pragma unroll
    for (int tt = 0; tt < 16; ++tt) {
        float p0 = 0.f, p1 = 0.f;
        const int t = tt * 16 + l15;
        #pragma unroll
        for (int r = 0; r < 4; ++r) {
            const int n = bn0 + wv * 16 + lg * 4 + r;
            const bool ok = n < NW;
            const int nc = ok ? n : NW - 1;
            const int j = nc / H_SZ;
            const int h = nc - j * H_SZ;
            const float sv = S[t * H_SZ + h];
            const float prod = ok ? acc[tt][r] * sv : 0.f;
            if (j == jlo) p0 += prod; else p1 += prod;
        }
        p0 += __shfl_xor(p0, 16, 64); p0 += __shfl_xor(p0, 32, 64);
        p1 += __shfl_xor(p1, 16, 64); p1 += __shfl_xor(p1, 32, 64);
        if (lg == 0) {
            if (p0 != 0.f) atomicAdd(&part[0][t], p0);
            if (p1 != 0.f) atomicAdd(&part[1][t], p1);
        }
    }
    __syncthreads();
    {
        const int b = tid >> 8, t = tid & 255;
        const int j = jlo + b;
        const float v = part[b][t];
        if (j < F_SZ && v != 0.f) atomicAdd(&zprime[t * F_SZ + j], v);
    }
}

// -------- K4a: z = zprime + A@W1 + t*(A@bupd) + b1 -> SELU -> ys (bf16 slab)
__global__ void __launch_bounds__(256) k4a_mfma(const short* __restrict__ Abf2,
                                                const float* __restrict__ W1,
                                                const float* __restrict__ bupd,
                                                const float* __restrict__ b1,
                                                const float* __restrict__ zprime,
                                                short* __restrict__ ysb) {
    const int tid = threadIdx.x;
    const int j0 = blockIdx.x * 16;
    const int w = tid >> 6, l = tid & 63;
    const int l15 = l & 15, lg = l >> 4;
    const int j = j0 + l15;
    const int jc = (j < F_SZ) ? j : F_SZ - 1;

    f32x4 acc1[4], acch[4], accl[4];
    #pragma unroll
    for (int tt = 0; tt < 4; ++tt) {
        acc1[tt] = (f32x4){0.f, 0.f, 0.f, 0.f};
        acch[tt] = (f32x4){0.f, 0.f, 0.f, 0.f};
        accl[tt] = (f32x4){0.f, 0.f, 0.f, 0.f};
    }

    for (int ks = 0; ks < 32; ++ks) {
        short8 a1, ah, al;
        #pragma unroll
        for (int e = 0; e < 8; ++e) {
            const int kk = ks * 32 + lg * 8 + e;
            a1[e] = f2bf(W1[kk * F_SZ + jc]);
            const float bu = bupd[kk * F_SZ + jc];
            const short hi = f2bf(bu);
            ah[e] = hi;
            al[e] = f2bf(bu - bf2f(hi));
        }
        #pragma unroll
        for (int tt = 0; tt < 4; ++tt) {
            const short* ap = Abf2 + (size_t)(ks * 4 + lg) * (T_SZ * 8)
                                   + (size_t)(w * 64 + tt * 16 + l15) * 8;
            short8 bfr = *reinterpret_cast<const short8*>(ap);
            acc1[tt] = __builtin_amdgcn_mfma_f32_16x16x32_bf16(a1, bfr, acc1[tt], 0, 0, 0);
            acch[tt] = __builtin_amdgcn_mfma_f32_16x16x32_bf16(ah, bfr, acch[tt], 0, 0, 0);
            accl[tt] = __builtin_amdgcn_mfma_f32_16x16x32_bf16(al, bfr, accl[tt], 0, 0, 0);
        }
    }
    const float scale = 1.0507009873554805f, alpha = 1.6732632423543772f;
    #pragma unroll
    for (int tt = 0; tt < 4; ++tt) {
        const int t = w * 64 + tt * 16 + l15;     // C col
        #pragma unroll
        for (int r = 0; r < 4; ++r) {
            const int jr = j0 + lg * 4 + r;       // C row
            short sv = 0;
            if (jr < F_SZ) {
                const float d2 = acch[tt][r] + accl[tt][r];
                float z = zprime[t * F_SZ + jr] + acc1[tt][r] + (float)t * d2 + b1[jr];
                float y = z > 0.f ? scale * z : scale * alpha * (expf(z) - 1.f);
                sv = f2bf(y);
            }
            ysb[(jr >> 3) * (T_SZ * 8) + t * 8 + (jr & 7)] = sv;   // jr < 256 always
        }
    }
}

// -------- K4b: out^T[o][t] = W2^T @ ys^T + b2. 16 blocks x 4 waves ----------
__global__ void __launch_bounds__(256) k4b_mfma(const short* __restrict__ ysb,
                                                const float* __restrict__ W2,
                                                const float* __restrict__ b2,
                                                float* __restrict__ out) {
    const int tid = threadIdx.x;
    const int o0 = (blockIdx.x & 7) * 64;     // o-group
    const int th = blockIdx.x >> 3;           // t-half
    const int w = tid >> 6, l = tid & 63;
    const int l15 = l & 15, lg = l >> 4;
    const int o = o0 + w * 16 + l15;

    f32x4 acc[8];
    #pragma unroll
    for (int tt = 0; tt < 8; ++tt) acc[tt] = (f32x4){0.f, 0.f, 0.f, 0.f};

    for (int ks = 0; ks < 8; ++ks) {          // K = 256 (250 real + 6 zero)
        short8 afr;
        #pragma unroll
        for (int e = 0; e < 8; ++e) {
            const int kk = ks * 32 + lg * 8 + e;
            afr[e] = (kk < F_SZ) ? f2bf(W2[kk * O_SZ + o]) : (short)0;
        }
        #pragma unroll
        for (int tt = 0; tt < 8; ++tt) {
            const short* ap = ysb + (size_t)(ks * 4 + lg) * (T_SZ * 8)
                                  + (size_t)(th * 128 + tt * 16 + l15) * 8;
            short8 bfr = *reinterpret_cast<const short8*>(ap);
            acc[tt] = __builtin_amdgcn_mfma_f32_16x16x32_bf16(afr, bfr, acc[tt], 0, 0, 0);
        }
    }
    #pragma unroll
    for (int tt = 0; tt < 8; ++tt) {
        const int t = th * 128 + tt * 16 + l15;
        #pragma unroll
        for (int r = 0; r < 4; ++r) {
            const int oo = o0 + w * 16 + lg * 4 + r;
            out[t * O_SZ + oo] = acc[tt][r] + b2[oo];
        }
    }
}

extern "C" void kernel_launch(void* const* d_in, const int* in_sizes, int n_in,
                              void* d_out, int out_size, void* d_ws, size_t ws_size,
                              hipStream_t stream) {
    const float* x    = (const float*)d_in[0];
    const float* h0   = (const float*)d_in[1];
    const float* Wrnn = (const float*)d_in[2];
    const float* brnn = (const float*)d_in[3];
    const float* Wupd = (const float*)d_in[4];
    const float* bupd = (const float*)d_in[5];
    const float* W1   = (const float*)d_in[6];
    const float* b1   = (const float*)d_in[7];
    const float* W2   = (const float*)d_in[8];
    const float* b2   = (const float*)d_in[9];
    float* out = (float*)d_out;

    float* ws = (float*)d_ws;
    float* P      = ws;                              // 48640
    float* h_all  = P + T_SZ * H_SZ;                 // 48640
    float* S      = h_all + T_SZ * H_SZ;             // 48640
    float* zprime = S + T_SZ * H_SZ;                 // 64000
    short* Abf2   = (short*)(zprime + T_SZ * F_SZ);  // 262144 shorts
    short* ysb    = Abf2 + 262144;                   // 65536 shorts (128 KB)

    hipMemsetAsync(zprime, 0, T_SZ * F_SZ * sizeof(float), stream);
    k2b_buildAx<<<T_SZ, 256, 0, stream>>>(x, Abf2);
    k1_mfma    <<<12,   256, 0, stream>>>(Abf2, Wrnn, brnn, P);
    k2_scan    <<<1,    256, 0, stream>>>(Wrnn, h0, P, h_all, S, Abf2);
    k3_mfma    <<<372,  512, 0, stream>>>(Wupd, Abf2, S, zprime);
    k4a_mfma   <<<16,   256, 0, stream>>>(Abf2, W1, bupd, b1, zprime, ysb);
    k4b_mfma   <<<16,   256, 0, stream>>>(ysb, W2, b2, out);
}

// Round 11
// 413.113 us; speedup vs baseline: 1.2292x; 1.2292x over previous
//
#include <hip/hip_runtime.h>
#include <hip/hip_bf16.h>

#define I_SZ 834
#define H_SZ 190
#define F_SZ 250
#define O_SZ 512
#define T_SZ 256
#define K_SZ 1024   // I+H
#define NW   47500  // F*H: Wupd flat IS W3[1024][47500] row-major

// Abf2 layout: value A[t][k] (bf16 of concat(x_t,h_t)) lives at
//   (k>>3)*2048 + t*8 + (k&7)   -> b128 fragment loads are 256-B coalesced,
//   and 4 consecutive k-slabs = 16 KB contiguous (one K-stage of staging).

typedef __attribute__((ext_vector_type(8))) short short8;
typedef __attribute__((ext_vector_type(4))) float f32x4;

__device__ __forceinline__ short f2bf(float f) {
    union { __hip_bfloat16 h; short s; } u;
    u.h = __float2bfloat16(f);
    return u.s;
}
__device__ __forceinline__ float bf2f(short s) {
    union { short s; __hip_bfloat16 h; } u;
    u.s = s;
    return __bfloat162float(u.h);
}

// async global->LDS, 16B per lane; LDS dest = wave-uniform base + lane*16
__device__ __forceinline__ void gll16(const void* g, void* l) {
    __builtin_amdgcn_global_load_lds(
        (const __attribute__((address_space(1))) void*)g,
        (__attribute__((address_space(3))) void*)l, 16, 0, 0);
}

// LDS-only barrier: drain lgkm (ds ops) but NOT vmcnt (global stores/loads
// stay in flight). __syncthreads would emit s_waitcnt vmcnt(0) -> ~400cy
// store drain on the scan's serial critical path.
__device__ __forceinline__ void lds_barrier() {
    asm volatile("s_waitcnt lgkmcnt(0)" ::: "memory");
    __builtin_amdgcn_s_barrier();
}

// -------- K2b: x-part of Abf2 + zero pad k in [834,864) ---------------------
__global__ void __launch_bounds__(256) k2b_buildAx(const float* __restrict__ x,
                                                   short* __restrict__ Abf2) {
    int t = blockIdx.x;
    for (int i = threadIdx.x; i < I_SZ; i += 256)
        Abf2[(i >> 3) * (T_SZ * 8) + t * 8 + (i & 7)] = f2bf(x[t * I_SZ + i]);
    for (int i = I_SZ + threadIdx.x; i < 864; i += 256)
        Abf2[(i >> 3) * (T_SZ * 8) + t * 8 + (i & 7)] = 0;
}

// -------- K1: P^T[h][t] = Wx^T @ x^T via MFMA (12 blocks x 4 waves) ---------
__global__ void __launch_bounds__(256) k1_mfma(const short* __restrict__ Abf2,
                                               const float* __restrict__ Wrnn,
                                               const float* __restrict__ brnn,
                                               float* __restrict__ P) {
    const int tid = threadIdx.x;
    const int bh = blockIdx.x;
    const int w = tid >> 6, l = tid & 63;
    const int l15 = l & 15, lg = l >> 4;
    const int h = bh * 16 + l15;
    const int hc = (h < H_SZ) ? h : H_SZ - 1;

    f32x4 acc[4];
    #pragma unroll
    for (int tt = 0; tt < 4; ++tt) acc[tt] = (f32x4){0.f, 0.f, 0.f, 0.f};

    for (int ks = 0; ks < 27; ++ks) {       // K = 864 (zero-padded past 834)
        short8 afr;
        #pragma unroll
        for (int e = 0; e < 8; ++e) {
            const int kk = ks * 32 + lg * 8 + e;
            float v = (kk < I_SZ && h < H_SZ) ? Wrnn[hc * K_SZ + H_SZ + kk] : 0.f;
            afr[e] = f2bf(v);
        }
        #pragma unroll
        for (int tt = 0; tt < 4; ++tt) {
            const short* ap = Abf2 + (size_t)(ks * 4 + lg) * (T_SZ * 8)
                                   + (size_t)(w * 64 + tt * 16 + l15) * 8;
            short8 bfr = *reinterpret_cast<const short8*>(ap);
            acc[tt] = __builtin_amdgcn_mfma_f32_16x16x32_bf16(afr, bfr, acc[tt], 0, 0, 0);
        }
    }
    #pragma unroll
    for (int tt = 0; tt < 4; ++tt) {
        const int t = w * 64 + tt * 16 + l15;
        #pragma unroll
        for (int r = 0; r < 4; ++r) {
            const int hrow = bh * 16 + lg * 4 + r;
            if (hrow < H_SZ) P[t * H_SZ + hrow] = acc[tt][r] + brnn[hrow];
        }
    }
}

// -------- K2 v5: MFMA scan, 8 waves = 4(n: 48 cols) x 2(k: 96) --------------
// B[3][3] = 36 VGPR/wave (2x headroom vs budget -- NO spill this time).
// Cross-k reduction via part[2][192] (round-9 validated numerics).
// Both per-step barriers are lgkm-only: global stores never drain in-loop.
__global__ void __launch_bounds__(512, 1) k2_scan(const float* __restrict__ Wrnn,
                                                  const float* __restrict__ h0,
                                                  const float* __restrict__ P,
                                                  float* __restrict__ h_all,
                                                  float* __restrict__ S,
                                                  short* __restrict__ Abf2) {
    __shared__ __align__(16) short hlds[2][192];
    __shared__ float part[2][192];
    const int tid = threadIdx.x;
    const int w = tid >> 6, l = tid & 63;
    const int wn = w & 3;               // n-quarter: 48 cols
    const int wk = w >> 2;              // k-half: 96 k
    const int l15 = l & 15, lg = l >> 4;
    const short8 zs = {0, 0, 0, 0, 0, 0, 0, 0};

    // one-time: this wave's Whh^T fragments (36 VGPR)
    short8 B[3][3];
    #pragma unroll
    for (int kt = 0; kt < 3; ++kt) {
        #pragma unroll
        for (int nt = 0; nt < 3; ++nt) {
            const int n = wn * 48 + nt * 16 + l15;
            short8 bf = zs;
            #pragma unroll
            for (int e = 0; e < 8; ++e) {
                const int kk = wk * 96 + kt * 32 + lg * 8 + e;
                float v = (n < H_SZ && kk < H_SZ) ? Wrnn[n * K_SZ + kk] : 0.f;
                bf[e] = f2bf(v);
            }
            B[kt][nt] = bf;
        }
    }
    if (tid < 192) {
        hlds[0][tid] = f2bf((tid < H_SZ) ? h0[tid] : 0.f);
        hlds[1][tid] = 0;               // pad slots 190,191 stay 0 forever
    }
    // scan ownership: thread tid (<190) owns row n = tid
    float Srun = 0.f;
    float pc = (tid < H_SZ) ? P[tid] : 0.f;
    lds_barrier();

    int rb = 0;
    #pragma unroll 1
    for (int t = 0; t < T_SZ; ++t) {
        // a-frags: broadcast h (this wave's k-half), mask rows != 0
        short8 a[3];
        #pragma unroll
        for (int kt = 0; kt < 3; ++kt) {
            short8 ar = *reinterpret_cast<const short8*>(
                &hlds[rb][wk * 96 + kt * 32 + lg * 8]);
            a[kt] = (l15 == 0) ? ar : zs;
        }
        // prefetch P[t+1]: consumed one full step later (vmcnt never drained)
        float pn = (t + 1 < T_SZ && tid < H_SZ) ? P[(t + 1) * H_SZ + tid] : 0.f;
        // 3 independent 3-deep MFMA chains
        f32x4 acc[3];
        #pragma unroll
        for (int nt = 0; nt < 3; ++nt) {
            f32x4 c = {0.f, 0.f, 0.f, 0.f};
            #pragma unroll
            for (int kt = 0; kt < 3; ++kt)
                c = __builtin_amdgcn_mfma_f32_16x16x32_bf16(a[kt], B[kt][nt], c, 0, 0, 0);
            acc[nt] = c;
        }
        if (l < 16) {                   // C row 0 = lanes 0..15, reg 0
            #pragma unroll
            for (int nt = 0; nt < 3; ++nt)
                part[wk][wn * 48 + nt * 16 + l] = acc[nt][0];
        }
        lds_barrier();                  // part visible; LDS-only drain
        if (tid < H_SZ) {
            float v = tanhf(part[0][tid] + part[1][tid] + pc);
            S[t * H_SZ + tid] = Srun;   // prefix EXCLUDING current step
            h_all[t * H_SZ + tid] = v;
            const int k = I_SZ + tid;
            Abf2[(k >> 3) * (T_SZ * 8) + t * 8 + (k & 7)] = f2bf(v);
            hlds[rb ^ 1][tid] = f2bf(v);    // write buffer != read buffer
            Srun += v;
        }
        lds_barrier();                  // h_{t+1} visible; stores stay in flight
        rb ^= 1;
        pc = pn;
    }
}

// -------- K3 v5: 2-phase gll-staged MFMA GEMM (zero global loads in K-loop) -
__global__ void __launch_bounds__(512) k3_mfma(const float* __restrict__ Wupd,
                                               const short* __restrict__ Abf2,
                                               const float* __restrict__ S,
                                               float* __restrict__ zprime) {
    __shared__ __align__(16) float Wlds[2][4096];    // [32 k][128 n] fp32
    __shared__ __align__(16) short Alds[2][8192];    // [4 g][256 t][8 k] bf16
    __shared__ float part[2][256];
    const int tid = threadIdx.x;
    const int bn0 = blockIdx.x * 128;
    const int l = tid & 63, wv = tid >> 6;
    const int l15 = l & 15, lg = l >> 4;

    part[tid >> 8][tid & 255] = 0.f;

    const char* src[4];
    long long stp[4];
    int cloc[4];
    #pragma unroll
    for (int i = 0; i < 4; ++i) {
        const int c = wv * 4 + i;
        cloc[i] = c;
        if (c < 16) {
            const int k = c * 2 + (l >> 5);          // 0..31
            const int n = (l & 31) * 4;              // 0..124
            const bool ok = (bn0 + n + 4) <= NW;     // NW % 4 == 0
            src[i] = (const char*)(Wupd + (size_t)k * NW + (ok ? (size_t)(bn0 + n) : 0));
            stp[i] = (long long)32 * NW * 4;
        } else {
            src[i] = (const char*)(Abf2 + (size_t)(c - 16) * 512 + (size_t)l * 8);
            stp[i] = 16384;
        }
    }

    f32x4 acc[16];
    #pragma unroll
    for (int tt = 0; tt < 16; ++tt) acc[tt] = (f32x4){0.f, 0.f, 0.f, 0.f};

    #pragma unroll
    for (int i = 0; i < 4; ++i) {
        void* dst = (cloc[i] < 16) ? (void*)&Wlds[0][cloc[i] * 256]
                                   : (void*)&Alds[0][(cloc[i] - 16) * 512];
        gll16(src[i], dst);
        src[i] += stp[i];
    }
    __syncthreads();

    int cur = 0;
    #pragma unroll 1
    for (int s = 0; s < 32; ++s) {
        if (s + 1 < 32) {                            // issue next stage FIRST
            #pragma unroll
            for (int i = 0; i < 4; ++i) {
                void* dst = (cloc[i] < 16) ? (void*)&Wlds[cur ^ 1][cloc[i] * 256]
                                           : (void*)&Alds[cur ^ 1][(cloc[i] - 16) * 512];
                gll16(src[i], dst);
                src[i] += stp[i];
            }
        }
        short8 afr;
        #pragma unroll
        for (int e = 0; e < 8; ++e)
            afr[e] = f2bf(Wlds[cur][(lg * 8 + e) * 128 + wv * 16 + l15]);
        #pragma unroll
        for (int tt = 0; tt < 16; ++tt) {
            short8 bfr = *reinterpret_cast<const short8*>(
                &Alds[cur][((size_t)lg * 256 + tt * 16 + l15) * 8]);
            acc[tt] = __builtin_amdgcn_mfma_f32_16x16x32_bf16(afr, bfr, acc[tt], 0, 0, 0);
        }
        __syncthreads();
        cur ^= 1;
    }

    const int jlo = bn0 / H_SZ;
    #pragma unroll
    for (int tt = 0; tt < 16; ++tt) {
        float p0 = 0.f, p1 = 0.f;
        const int t = tt * 16 + l15;
        #pragma unroll
        for (int r = 0; r < 4; ++r) {
            const int n = bn0 + wv * 16 + lg * 4 + r;
            const bool ok = n < NW;
            const int nc = ok ? n : NW - 1;
            const int j = nc / H_SZ;
            const int h = nc - j * H_SZ;
            const float sv = S[t * H_SZ + h];
            const float prod = ok ? acc[tt][r] * sv : 0.f;
            if (j == jlo) p0 += prod; else p1 += prod;
        }
        p0 += __shfl_xor(p0, 16, 64); p0 += __shfl_xor(p0, 32, 64);
        p1 += __shfl_xor(p1, 16, 64); p1 += __shfl_xor(p1, 32, 64);
        if (lg == 0) {
            if (p0 != 0.f) atomicAdd(&part[0][t], p0);
            if (p1 != 0.f) atomicAdd(&part[1][t], p1);
        }
    }
    __syncthreads();
    {
        const int b = tid >> 8, t = tid & 255;
        const int j = jlo + b;
        const float v = part[b][t];
        if (j < F_SZ && v != 0.f) atomicAdd(&zprime[t * F_SZ + j], v);
    }
}

// -------- K4a: z = zprime + A@W1 + t*(A@bupd) + b1 -> SELU -> ys (bf16 slab)
__global__ void __launch_bounds__(256) k4a_mfma(const short* __restrict__ Abf2,
                                                const float* __restrict__ W1,
                                                const float* __restrict__ bupd,
                                                const float* __restrict__ b1,
                                                const float* __restrict__ zprime,
                                                short* __restrict__ ysb) {
    const int tid = threadIdx.x;
    const int j0 = blockIdx.x * 16;
    const int w = tid >> 6, l = tid & 63;
    const int l15 = l & 15, lg = l >> 4;
    const int j = j0 + l15;
    const int jc = (j < F_SZ) ? j : F_SZ - 1;

    f32x4 acc1[4], acch[4], accl[4];
    #pragma unroll
    for (int tt = 0; tt < 4; ++tt) {
        acc1[tt] = (f32x4){0.f, 0.f, 0.f, 0.f};
        acch[tt] = (f32x4){0.f, 0.f, 0.f, 0.f};
        accl[tt] = (f32x4){0.f, 0.f, 0.f, 0.f};
    }

    for (int ks = 0; ks < 32; ++ks) {
        short8 a1, ah, al;
        #pragma unroll
        for (int e = 0; e < 8; ++e) {
            const int kk = ks * 32 + lg * 8 + e;
            a1[e] = f2bf(W1[kk * F_SZ + jc]);
            const float bu = bupd[kk * F_SZ + jc];
            const short hi = f2bf(bu);
            ah[e] = hi;
            al[e] = f2bf(bu - bf2f(hi));
        }
        #pragma unroll
        for (int tt = 0; tt < 4; ++tt) {
            const short* ap = Abf2 + (size_t)(ks * 4 + lg) * (T_SZ * 8)
                                   + (size_t)(w * 64 + tt * 16 + l15) * 8;
            short8 bfr = *reinterpret_cast<const short8*>(ap);
            acc1[tt] = __builtin_amdgcn_mfma_f32_16x16x32_bf16(a1, bfr, acc1[tt], 0, 0, 0);
            acch[tt] = __builtin_amdgcn_mfma_f32_16x16x32_bf16(ah, bfr, acch[tt], 0, 0, 0);
            accl[tt] = __builtin_amdgcn_mfma_f32_16x16x32_bf16(al, bfr, accl[tt], 0, 0, 0);
        }
    }
    const float scale = 1.0507009873554805f, alpha = 1.6732632423543772f;
    #pragma unroll
    for (int tt = 0; tt < 4; ++tt) {
        const int t = w * 64 + tt * 16 + l15;     // C col
        #pragma unroll
        for (int r = 0; r < 4; ++r) {
            const int jr = j0 + lg * 4 + r;       // C row
            short sv = 0;
            if (jr < F_SZ) {
                const float d2 = acch[tt][r] + accl[tt][r];
                float z = zprime[t * F_SZ + jr] + acc1[tt][r] + (float)t * d2 + b1[jr];
                float y = z > 0.f ? scale * z : scale * alpha * (expf(z) - 1.f);
                sv = f2bf(y);
            }
            ysb[(jr >> 3) * (T_SZ * 8) + t * 8 + (jr & 7)] = sv;   // jr < 256 always
        }
    }
}

// -------- K4b: out^T[o][t] = W2^T @ ys^T + b2. 16 blocks x 4 waves ----------
__global__ void __launch_bounds__(256) k4b_mfma(const short* __restrict__ ysb,
                                                const float* __restrict__ W2,
                                                const float* __restrict__ b2,
                                                float* __restrict__ out) {
    const int tid = threadIdx.x;
    const int o0 = (blockIdx.x & 7) * 64;     // o-group
    const int th = blockIdx.x >> 3;           // t-half
    const int w = tid >> 6, l = tid & 63;
    const int l15 = l & 15, lg = l >> 4;
    const int o = o0 + w * 16 + l15;

    f32x4 acc[8];
    #pragma unroll
    for (int tt = 0; tt < 8; ++tt) acc[tt] = (f32x4){0.f, 0.f, 0.f, 0.f};

    for (int ks = 0; ks < 8; ++ks) {          // K = 256 (250 real + 6 zero)
        short8 afr;
        #pragma unroll
        for (int e = 0; e < 8; ++e) {
            const int kk = ks * 32 + lg * 8 + e;
            afr[e] = (kk < F_SZ) ? f2bf(W2[kk * O_SZ + o]) : (short)0;
        }
        #pragma unroll
        for (int tt = 0; tt < 8; ++tt) {
            const short* ap = ysb + (size_t)(ks * 4 + lg) * (T_SZ * 8)
                                  + (size_t)(th * 128 + tt * 16 + l15) * 8;
            short8 bfr = *reinterpret_cast<const short8*>(ap);
            acc[tt] = __builtin_amdgcn_mfma_f32_16x16x32_bf16(afr, bfr, acc[tt], 0, 0, 0);
        }
    }
    #pragma unroll
    for (int tt = 0; tt < 8; ++tt) {
        const int t = th * 128 + tt * 16 + l15;
        #pragma unroll
        for (int r = 0; r < 4; ++r) {
            const int oo = o0 + w * 16 + lg * 4 + r;
            out[t * O_SZ + oo] = acc[tt][r] + b2[oo];
        }
    }
}

extern "C" void kernel_launch(void* const* d_in, const int* in_sizes, int n_in,
                              void* d_out, int out_size, void* d_ws, size_t ws_size,
                              hipStream_t stream) {
    const float* x    = (const float*)d_in[0];
    const float* h0   = (const float*)d_in[1];
    const float* Wrnn = (const float*)d_in[2];
    const float* brnn = (const float*)d_in[3];
    const float* Wupd = (const float*)d_in[4];
    const float* bupd = (const float*)d_in[5];
    const float* W1   = (const float*)d_in[6];
    const float* b1   = (const float*)d_in[7];
    const float* W2   = (const float*)d_in[8];
    const float* b2   = (const float*)d_in[9];
    float* out = (float*)d_out;

    float* ws = (float*)d_ws;
    float* P      = ws;                              // 48640
    float* h_all  = P + T_SZ * H_SZ;                 // 48640
    float* S      = h_all + T_SZ * H_SZ;             // 48640
    float* zprime = S + T_SZ * H_SZ;                 // 64000
    short* Abf2   = (short*)(zprime + T_SZ * F_SZ);  // 262144 shorts
    short* ysb    = Abf2 + 262144;                   // 65536 shorts (128 KB)

    hipMemsetAsync(zprime, 0, T_SZ * F_SZ * sizeof(float), stream);
    k2b_buildAx<<<T_SZ, 256, 0, stream>>>(x, Abf2);
    k1_mfma    <<<12,   256, 0, stream>>>(Abf2, Wrnn, brnn, P);
    k2_scan    <<<1,    512, 0, stream>>>(Wrnn, h0, P, h_all, S, Abf2);
    k3_mfma    <<<372,  512, 0, stream>>>(Wupd, Abf2, S, zprime);
    k4a_mfma   <<<16,   256, 0, stream>>>(Abf2, W1, bupd, b1, zprime, ysb);
    k4b_mfma   <<<16,   256, 0, stream>>>(ysb, W2, b2, out);
}

// Round 12
// 350.115 us; speedup vs baseline: 1.4504x; 1.1799x over previous
//
#include <hip/hip_runtime.h>
#include <hip/hip_bf16.h>

#define I_SZ 834
#define H_SZ 190
#define F_SZ 250
#define O_SZ 512
#define T_SZ 256
#define K_SZ 1024   // I+H
#define NW   47500  // F*H: Wupd flat IS W3[1024][47500] row-major

// Abf2 layout: value A[t][k] (bf16 of concat(x_t,h_t)) lives at
//   (k>>3)*2048 + t*8 + (k&7)   -> b128 fragment loads are 256-B coalesced,
//   and 4 consecutive k-slabs = 16 KB contiguous (one K-stage of staging).

typedef __attribute__((ext_vector_type(8))) short short8;
typedef __attribute__((ext_vector_type(4))) float f32x4;

__device__ __forceinline__ short f2bf(float f) {
    union { __hip_bfloat16 h; short s; } u;
    u.h = __float2bfloat16(f);
    return u.s;
}
__device__ __forceinline__ float bf2f(short s) {
    union { short s; __hip_bfloat16 h; } u;
    u.s = s;
    return __bfloat162float(u.h);
}

// async global->LDS, 16B per lane; LDS dest = wave-uniform base + lane*16
__device__ __forceinline__ void gll16(const void* g, void* l) {
    __builtin_amdgcn_global_load_lds(
        (const __attribute__((address_space(1))) void*)g,
        (__attribute__((address_space(3))) void*)l, 16, 0, 0);
}

// LDS-only barrier: drain lgkm (ds ops) but NOT vmcnt.
__device__ __forceinline__ void lds_barrier() {
    asm volatile("s_waitcnt lgkmcnt(0)" ::: "memory");
    __builtin_amdgcn_s_barrier();
}

// branch-free tanh: 1 - 2/(e^{2x}+1); exp overflow/underflow saturate to +/-1
__device__ __forceinline__ float fast_tanh(float x) {
    const float e = __expf(2.f * x);
    return 1.f - 2.f / (e + 1.f);
}

// -------- K2b: x-part of Abf2 + zero pad k in [834,864) ---------------------
__global__ void __launch_bounds__(256) k2b_buildAx(const float* __restrict__ x,
                                                   short* __restrict__ Abf2) {
    int t = blockIdx.x;
    for (int i = threadIdx.x; i < I_SZ; i += 256)
        Abf2[(i >> 3) * (T_SZ * 8) + t * 8 + (i & 7)] = f2bf(x[t * I_SZ + i]);
    for (int i = I_SZ + threadIdx.x; i < 864; i += 256)
        Abf2[(i >> 3) * (T_SZ * 8) + t * 8 + (i & 7)] = 0;
}

// -------- K1: P^T[h][t] = Wx^T @ x^T via MFMA (12 blocks x 4 waves) ---------
__global__ void __launch_bounds__(256) k1_mfma(const short* __restrict__ Abf2,
                                               const float* __restrict__ Wrnn,
                                               const float* __restrict__ brnn,
                                               float* __restrict__ P) {
    const int tid = threadIdx.x;
    const int bh = blockIdx.x;
    const int w = tid >> 6, l = tid & 63;
    const int l15 = l & 15, lg = l >> 4;
    const int h = bh * 16 + l15;
    const int hc = (h < H_SZ) ? h : H_SZ - 1;

    f32x4 acc[4];
    #pragma unroll
    for (int tt = 0; tt < 4; ++tt) acc[tt] = (f32x4){0.f, 0.f, 0.f, 0.f};

    for (int ks = 0; ks < 27; ++ks) {       // K = 864 (zero-padded past 834)
        short8 afr;
        #pragma unroll
        for (int e = 0; e < 8; ++e) {
            const int kk = ks * 32 + lg * 8 + e;
            float v = (kk < I_SZ && h < H_SZ) ? Wrnn[hc * K_SZ + H_SZ + kk] : 0.f;
            afr[e] = f2bf(v);
        }
        #pragma unroll
        for (int tt = 0; tt < 4; ++tt) {
            const short* ap = Abf2 + (size_t)(ks * 4 + lg) * (T_SZ * 8)
                                   + (size_t)(w * 64 + tt * 16 + l15) * 8;
            short8 bfr = *reinterpret_cast<const short8*>(ap);
            acc[tt] = __builtin_amdgcn_mfma_f32_16x16x32_bf16(afr, bfr, acc[tt], 0, 0, 0);
        }
    }
    #pragma unroll
    for (int tt = 0; tt < 4; ++tt) {
        const int t = w * 64 + tt * 16 + l15;
        #pragma unroll
        for (int r = 0; r < 4; ++r) {
            const int hrow = bh * 16 + lg * 4 + r;
            if (hrow < H_SZ) P[t * H_SZ + hrow] = acc[tt][r] + brnn[hrow];
        }
    }
}

// -------- K2 v6: MFMA scan, 12 waves x 16 n-cols, full k per wave -----------
// B[6] = 24 VGPR/wave; 6 INDEPENDENT MFMAs (C=0) + VALU sum kill the 3-deep
// dependent-chain latency; no cross-wave reduction; ONE lgkm barrier/step;
// branch-free tanh; dead h_all store removed.
__global__ void __launch_bounds__(768, 1) k2_scan(const float* __restrict__ Wrnn,
                                                  const float* __restrict__ h0,
                                                  const float* __restrict__ P,
                                                  float* __restrict__ S,
                                                  short* __restrict__ Abf2) {
    __shared__ __align__(16) short hlds[2][192];
    const int tid = threadIdx.x;
    const int w = tid >> 6, l = tid & 63;
    const int l15 = l & 15, lg = l >> 4;
    const short8 zs = {0, 0, 0, 0, 0, 0, 0, 0};
    const int n = w * 16 + l15;             // wave w owns n-cols [w*16, w*16+16)
    const bool nok = n < H_SZ;

    // one-time: this wave's Whh^T fragments (24 VGPR)
    short8 B[6];
    #pragma unroll
    for (int kt = 0; kt < 6; ++kt) {
        short8 bf = zs;
        #pragma unroll
        for (int e = 0; e < 8; ++e) {
            const int kk = kt * 32 + lg * 8 + e;
            float v = (nok && kk < H_SZ) ? Wrnn[n * K_SZ + kk] : 0.f;
            bf[e] = f2bf(v);
        }
        B[kt] = bf;
    }
    if (tid < 192) {
        hlds[0][tid] = f2bf((tid < H_SZ) ? h0[tid] : 0.f);
        hlds[1][tid] = 0;                   // pad slots 190,191 stay 0 forever
    }
    float Srun = 0.f;
    float pc = (l < 16 && nok) ? P[n] : 0.f;
    lds_barrier();

    int rb = 0;
    #pragma unroll 1
    for (int t = 0; t < T_SZ; ++t) {
        short8 a[6];
        #pragma unroll
        for (int kt = 0; kt < 6; ++kt) {
            short8 ar = *reinterpret_cast<const short8*>(&hlds[rb][kt * 32 + lg * 8]);
            a[kt] = (l15 == 0) ? ar : zs;
        }
        const float pn = (t + 1 < T_SZ && l < 16 && nok) ? P[(t + 1) * H_SZ + n] : 0.f;
        f32x4 c[6];
        #pragma unroll
        for (int kt = 0; kt < 6; ++kt) {
            const f32x4 z4 = {0.f, 0.f, 0.f, 0.f};
            c[kt] = __builtin_amdgcn_mfma_f32_16x16x32_bf16(a[kt], B[kt], z4, 0, 0, 0);
        }
        if (l < 16 && nok) {
            const float s = ((c[0][0] + c[1][0]) + (c[2][0] + c[3][0]))
                          + (c[4][0] + c[5][0]) + pc;
            const float v = fast_tanh(s);
            S[t * H_SZ + n] = Srun;         // prefix EXCLUDING current step
            const int k = I_SZ + n;
            Abf2[(k >> 3) * (T_SZ * 8) + t * 8 + (k & 7)] = f2bf(v);
            hlds[rb ^ 1][n] = f2bf(v);      // write buffer != read buffer
            Srun += v;
        }
        lds_barrier();                      // single LDS-only barrier per step
        rb ^= 1;
        pc = pn;
    }
}

// -------- K3 v5: 2-phase gll-staged MFMA GEMM (zero global loads in K-loop) -
__global__ void __launch_bounds__(512) k3_mfma(const float* __restrict__ Wupd,
                                               const short* __restrict__ Abf2,
                                               const float* __restrict__ S,
                                               float* __restrict__ zprime) {
    __shared__ __align__(16) float Wlds[2][4096];    // [32 k][128 n] fp32
    __shared__ __align__(16) short Alds[2][8192];    // [4 g][256 t][8 k] bf16
    __shared__ float part[2][256];
    const int tid = threadIdx.x;
    const int bn0 = blockIdx.x * 128;
    const int l = tid & 63, wv = tid >> 6;
    const int l15 = l & 15, lg = l >> 4;

    part[tid >> 8][tid & 255] = 0.f;

    const char* src[4];
    long long stp[4];
    int cloc[4];
    #pragma unroll
    for (int i = 0; i < 4; ++i) {
        const int c = wv * 4 + i;
        cloc[i] = c;
        if (c < 16) {
            const int k = c * 2 + (l >> 5);          // 0..31
            const int n = (l & 31) * 4;              // 0..124
            const bool ok = (bn0 + n + 4) <= NW;     // NW % 4 == 0
            src[i] = (const char*)(Wupd + (size_t)k * NW + (ok ? (size_t)(bn0 + n) : 0));
            stp[i] = (long long)32 * NW * 4;
        } else {
            src[i] = (const char*)(Abf2 + (size_t)(c - 16) * 512 + (size_t)l * 8);
            stp[i] = 16384;
        }
    }

    f32x4 acc[16];
    #pragma unroll
    for (int tt = 0; tt < 16; ++tt) acc[tt] = (f32x4){0.f, 0.f, 0.f, 0.f};

    #pragma unroll
    for (int i = 0; i < 4; ++i) {
        void* dst = (cloc[i] < 16) ? (void*)&Wlds[0][cloc[i] * 256]
                                   : (void*)&Alds[0][(cloc[i] - 16) * 512];
        gll16(src[i], dst);
        src[i] += stp[i];
    }
    __syncthreads();

    int cur = 0;
    #pragma unroll 1
    for (int s = 0; s < 32; ++s) {
        if (s + 1 < 32) {                            // issue next stage FIRST
            #pragma unroll
            for (int i = 0; i < 4; ++i) {
                void* dst = (cloc[i] < 16) ? (void*)&Wlds[cur ^ 1][cloc[i] * 256]
                                           : (void*)&Alds[cur ^ 1][(cloc[i] - 16) * 512];
                gll16(src[i], dst);
                src[i] += stp[i];
            }
        }
        short8 afr;
        #pragma unroll
        for (int e = 0; e < 8; ++e)
            afr[e] = f2bf(Wlds[cur][(lg * 8 + e) * 128 + wv * 16 + l15]);
        #pragma unroll
        for (int tt = 0; tt < 16; ++tt) {
            short8 bfr = *reinterpret_cast<const short8*>(
                &Alds[cur][((size_t)lg * 256 + tt * 16 + l15) * 8]);
            acc[tt] = __builtin_amdgcn_mfma_f32_16x16x32_bf16(afr, bfr, acc[tt], 0, 0, 0);
        }
        __syncthreads();
        cur ^= 1;
    }

    const int jlo = bn0 / H_SZ;
    #pragma unroll
    for (int tt = 0; tt < 16; ++tt) {
        float p0 = 0.f, p1 = 0.f;
        const int t = tt * 16 + l15;
        #pragma unroll
        for (int r = 0; r < 4; ++r) {
            const int n = bn0 + wv * 16 + lg * 4 + r;
            const bool ok = n < NW;
            const int nc = ok ? n : NW - 1;
            const int j = nc / H_SZ;
            const int h = nc - j * H_SZ;
            const float sv = S[t * H_SZ + h];
            const float prod = ok ? acc[tt][r] * sv : 0.f;
            if (j == jlo) p0 += prod; else p1 += prod;
        }
        p0 += __shfl_xor(p0, 16, 64); p0 += __shfl_xor(p0, 32, 64);
        p1 += __shfl_xor(p1, 16, 64); p1 += __shfl_xor(p1, 32, 64);
        if (lg == 0) {
            if (p0 != 0.f) atomicAdd(&part[0][t], p0);
            if (p1 != 0.f) atomicAdd(&part[1][t], p1);
        }
    }
    __syncthreads();
    {
        const int b = tid >> 8, t = tid & 255;
        const int j = jlo + b;
        const float v = part[b][t];
        if (j < F_SZ && v != 0.f) atomicAdd(&zprime[t * F_SZ + j], v);
    }
}

// -------- K4a v2: 256 one-wave blocks (16 j-tiles x 16 t-tiles) -------------
// z = zprime + A@W1 + t*(A@bupd) + b1 -> SELU -> ys (bf16 slab).
__global__ void __launch_bounds__(64) k4a_mfma(const short* __restrict__ Abf2,
                                               const float* __restrict__ W1,
                                               const float* __restrict__ bupd,
                                               const float* __restrict__ b1,
                                               const float* __restrict__ zprime,
                                               short* __restrict__ ysb) {
    const int l = threadIdx.x;
    const int j0 = (blockIdx.x & 15) * 16;
    const int th = blockIdx.x >> 4;           // 0..15: 16 t each
    const int l15 = l & 15, lg = l >> 4;
    const int jc = j0 + l15;
    const int jl = (jc < F_SZ) ? jc : F_SZ - 1;

    f32x4 acc1 = {0.f, 0.f, 0.f, 0.f};
    f32x4 acch = {0.f, 0.f, 0.f, 0.f};
    f32x4 accl = {0.f, 0.f, 0.f, 0.f};

    for (int ks = 0; ks < 32; ++ks) {
        short8 a1, ah, al;
        #pragma unroll
        for (int e = 0; e < 8; ++e) {
            const int kk = ks * 32 + lg * 8 + e;
            a1[e] = f2bf(W1[kk * F_SZ + jl]);
            const float bu = bupd[kk * F_SZ + jl];
            const short hi = f2bf(bu);
            ah[e] = hi;
            al[e] = f2bf(bu - bf2f(hi));
        }
        const short* ap = Abf2 + (size_t)(ks * 4 + lg) * (T_SZ * 8)
                               + (size_t)(th * 16 + l15) * 8;
        short8 bfr = *reinterpret_cast<const short8*>(ap);
        acc1 = __builtin_amdgcn_mfma_f32_16x16x32_bf16(a1, bfr, acc1, 0, 0, 0);
        acch = __builtin_amdgcn_mfma_f32_16x16x32_bf16(ah, bfr, acch, 0, 0, 0);
        accl = __builtin_amdgcn_mfma_f32_16x16x32_bf16(al, bfr, accl, 0, 0, 0);
    }
    const float scale = 1.0507009873554805f, alpha = 1.6732632423543772f;
    const int t = th * 16 + l15;              // C col
    #pragma unroll
    for (int r = 0; r < 4; ++r) {
        const int jr = j0 + lg * 4 + r;       // C row
        short sv = 0;
        if (jr < F_SZ) {
            const float d2 = acch[r] + accl[r];
            float z = zprime[t * F_SZ + jr] + acc1[r] + (float)t * d2 + b1[jr];
            float y = z > 0.f ? scale * z : scale * alpha * (expf(z) - 1.f);
            sv = f2bf(y);
        }
        ysb[(jr >> 3) * (T_SZ * 8) + t * 8 + (jr & 7)] = sv;   // jr < 256 always
    }
}

// -------- K4b v2: 256 one-wave blocks (32 o-tiles x 8 t-tiles of 32 t) ------
__global__ void __launch_bounds__(64) k4b_mfma(const short* __restrict__ ysb,
                                               const float* __restrict__ W2,
                                               const float* __restrict__ b2,
                                               float* __restrict__ out) {
    const int l = threadIdx.x;
    const int o0 = (blockIdx.x & 31) * 16;
    const int th = blockIdx.x >> 5;           // 0..7: 32 t each
    const int l15 = l & 15, lg = l >> 4;
    const int o = o0 + l15;

    f32x4 acc[2];
    acc[0] = (f32x4){0.f, 0.f, 0.f, 0.f};
    acc[1] = (f32x4){0.f, 0.f, 0.f, 0.f};

    for (int ks = 0; ks < 8; ++ks) {          // K = 256 (250 real + 6 zero)
        short8 afr;
        #pragma unroll
        for (int e = 0; e < 8; ++e) {
            const int kk = ks * 32 + lg * 8 + e;
            afr[e] = (kk < F_SZ) ? f2bf(W2[kk * O_SZ + o]) : (short)0;
        }
        #pragma unroll
        for (int tt = 0; tt < 2; ++tt) {
            const short* ap = ysb + (size_t)(ks * 4 + lg) * (T_SZ * 8)
                                  + (size_t)(th * 32 + tt * 16 + l15) * 8;
            short8 bfr = *reinterpret_cast<const short8*>(ap);
            acc[tt] = __builtin_amdgcn_mfma_f32_16x16x32_bf16(afr, bfr, acc[tt], 0, 0, 0);
        }
    }
    #pragma unroll
    for (int tt = 0; tt < 2; ++tt) {
        const int t = th * 32 + tt * 16 + l15;
        #pragma unroll
        for (int r = 0; r < 4; ++r) {
            const int oo = o0 + lg * 4 + r;
            out[t * O_SZ + oo] = acc[tt][r] + b2[oo];
        }
    }
}

extern "C" void kernel_launch(void* const* d_in, const int* in_sizes, int n_in,
                              void* d_out, int out_size, void* d_ws, size_t ws_size,
                              hipStream_t stream) {
    const float* x    = (const float*)d_in[0];
    const float* h0   = (const float*)d_in[1];
    const float* Wrnn = (const float*)d_in[2];
    const float* brnn = (const float*)d_in[3];
    const float* Wupd = (const float*)d_in[4];
    const float* bupd = (const float*)d_in[5];
    const float* W1   = (const float*)d_in[6];
    const float* b1   = (const float*)d_in[7];
    const float* W2   = (const float*)d_in[8];
    const float* b2   = (const float*)d_in[9];
    float* out = (float*)d_out;

    float* ws = (float*)d_ws;
    float* P      = ws;                              // 48640
    float* h_all  = P + T_SZ * H_SZ;                 // 48640 (slot kept, unused)
    float* S      = h_all + T_SZ * H_SZ;             // 48640
    float* zprime = S + T_SZ * H_SZ;                 // 64000
    short* Abf2   = (short*)(zprime + T_SZ * F_SZ);  // 262144 shorts
    short* ysb    = Abf2 + 262144;                   // 65536 shorts (128 KB)

    hipMemsetAsync(zprime, 0, T_SZ * F_SZ * sizeof(float), stream);
    k2b_buildAx<<<T_SZ, 256, 0, stream>>>(x, Abf2);
    k1_mfma    <<<12,   256, 0, stream>>>(Abf2, Wrnn, brnn, P);
    k2_scan    <<<1,    768, 0, stream>>>(Wrnn, h0, P, S, Abf2);
    k3_mfma    <<<372,  512, 0, stream>>>(Wupd, Abf2, S, zprime);
    k4a_mfma   <<<256,  64,  0, stream>>>(Abf2, W1, bupd, b1, zprime, ysb);
    k4b_mfma   <<<256,  64,  0, stream>>>(ysb, W2, b2, out);
}